// Round 10
// baseline (755.149 us; speedup 1.0000x reference)
//
#include <hip/hip_runtime.h>
#include <hip/hip_cooperative_groups.h>
#include <hip/hip_fp16.h>
#include <math.h>

namespace cg = cooperative_groups;

#define N_NODES 100000
#define N_EDGES 3200000
#define IN_CH   256
#define HID     64
#define OUTC    32
#define BSHIFT  7                         // 128-node buckets
#define BNODES  128
#define NBUCK   ((N_NODES + BNODES - 1) / BNODES)   // 782 buckets
#define CHUNK   4096                      // edges per partition block
#define EPT     16                        // edges per thread (CHUNK/256)
#define CAP     4608                      // bucket capacity: mean 4092 + ~8 sigma
#define NPART   ((N_EDGES + CHUNK - 1) / CHUNK)     // 782 partition blocks
#define NG1     ((N_NODES + 127) / 128)             // 782 gemm1 blocks

// ---------------- workspace layout (bytes) ----------------
static constexpr size_t align256(size_t x) { return (x + 255) & ~(size_t)255; }
static constexpr size_t OFF_PTRB = 0;                                          // N ints
static constexpr size_t OFF_PTRE = OFF_PTRB + align256((size_t)N_NODES * 4);   // N ints
static constexpr size_t OFF_GCUR = OFF_PTRE + align256((size_t)N_NODES * 4);   // NBUCK ints (memset 0)
static constexpr size_t OFF_DIS  = OFF_GCUR + align256((size_t)NBUCK * 4);     // N floats
static constexpr size_t OFF_SRC  = OFF_DIS  + align256((size_t)N_NODES * 4);   // NBUCK*CAP ints
static constexpr size_t OFF_PART = OFF_SRC  + align256((size_t)NBUCK * CAP * 4); // 14.4 MB
static constexpr size_t OFF_S1   = OFF_PART + align256((size_t)NBUCK * CAP * 4); // N*64 halves
static constexpr size_t OFF_S2   = OFF_S1   + align256((size_t)N_NODES * HID * 2); // N*32 halves

typedef _Float16 f16;
typedef f16 f16x8 __attribute__((ext_vector_type(8)));
typedef float f32x4 __attribute__((ext_vector_type(4)));

// unpack one 16 B chunk (8 halves) and accumulate into 8 fp32 accumulators
__device__ __forceinline__ void acc8(float* acc, float4 raw) {
    const __half2* hp = (const __half2*)&raw;
    float2 f0 = __half22float2(hp[0]);
    float2 f1 = __half22float2(hp[1]);
    float2 f2 = __half22float2(hp[2]);
    float2 f3 = __half22float2(hp[3]);
    acc[0] += f0.x; acc[1] += f0.y; acc[2] += f1.x; acc[3] += f1.y;
    acc[4] += f2.x; acc[5] += f2.y; acc[6] += f3.x; acc[7] += f3.y;
}

// ================= FUSED partition + gemm1 (unchanged, measured 92.4 us) =========
__device__ __forceinline__ void partition_body(int pb, const int* __restrict__ row,
                                               const int* __restrict__ col,
                                               int* __restrict__ gcur,
                                               int* __restrict__ part,
                                               char* smem) {
    int* lhist = (int*)smem;            // NBUCK ints
    int* lbase = lhist + NBUCK;         // NBUCK ints (relative base in bucket)
    const int t  = threadIdx.x;
    const int e0 = pb * CHUNK;
    for (int i = t; i < NBUCK; i += 256) lhist[i] = 0;
    __syncthreads();

    int pk[EPT], br[EPT];
#pragma unroll
    for (int i = 0; i < EPT; ++i) {
        int e = e0 + i * 256 + t;
        if (e < N_EDGES) {
            int d = col[e];
            int b = d >> BSHIFT;
            int r = atomicAdd(&lhist[b], 1);
            pk[i] = row[e] | ((d & (BNODES - 1)) << 17);
            br[i] = b | (r << 10);
        } else {
            br[i] = -1;
        }
    }
    __syncthreads();

    const int off = (int)((pb * 131u) % NBUCK);
    for (int i = t; i < NBUCK; i += 256) {
        int bb = i + off;
        if (bb >= NBUCK) bb -= NBUCK;
        int c = lhist[bb];
        lbase[bb] = (c > 0) ? atomicAdd(&gcur[bb], c) : 0;
    }
    __syncthreads();

#pragma unroll
    for (int i = 0; i < EPT; ++i) {
        if (br[i] >= 0) {
            int b = br[i] & 1023;
            int r = br[i] >> 10;
            part[b * CAP + lbase[b] + r] = pk[i];
        }
    }
}

__device__ __forceinline__ void gemm1_body(int gb, const float* __restrict__ x,
                                           const float* __restrict__ W1,
                                           __half* __restrict__ s1h,
                                           char* lds_raw) {
    f16* xh  = (f16*)lds_raw;              // [128][40] halves
    f16* xl  = (f16*)(lds_raw + 10240);
    f16* wth = (f16*)(lds_raw + 20480);    // [64][40] W^T hi chunk
    f16* wtl = (f16*)(lds_raw + 25600);

    const int t    = threadIdx.x;
    const int row0 = gb * 128;
    const int lane = t & 63;
    const int wv   = t >> 6;
    const int lr   = lane & 15;
    const int kg   = lane >> 4;

    f32x4 acc[2][4];
#pragma unroll
    for (int m = 0; m < 2; ++m)
#pragma unroll
        for (int n = 0; n < 4; ++n) acc[m][n] = (f32x4){0.f, 0.f, 0.f, 0.f};

    for (int kt = 0; kt < 8; ++kt) {
#pragma unroll
        for (int i = 0; i < 4; ++i) {
            int L  = i * 256 + t;
            int r  = L >> 3;
            int k4 = L & 7;
            int rg = row0 + r;
            float4 v = make_float4(0.f, 0.f, 0.f, 0.f);
            if (rg < N_NODES)
                v = ((const float4*)x)[(size_t)rg * 64 + kt * 8 + k4];
            union { f16 h[4]; unsigned long long u; } ph, pl;
            const float* vf = (const float*)&v;
#pragma unroll
            for (int c = 0; c < 4; ++c) {
                f16 hi = (f16)vf[c];
                ph.h[c] = hi;
                pl.h[c] = (f16)(vf[c] - (float)hi);
            }
            *(unsigned long long*)(&xh[r * 40 + k4 * 4]) = ph.u;
            *(unsigned long long*)(&xl[r * 40 + k4 * 4]) = pl.u;
        }
#pragma unroll
        for (int i = 0; i < 2; ++i) {
            int L  = i * 256 + t;
            int k  = L >> 4;
            int j4 = L & 15;
            float4 v = ((const float4*)W1)[(size_t)(kt * 32 + k) * 16 + j4];
            const float* vf = (const float*)&v;
#pragma unroll
            for (int c = 0; c < 4; ++c) {
                f16 hi = (f16)vf[c];
                wth[(j4 * 4 + c) * 40 + k] = hi;
                wtl[(j4 * 4 + c) * 40 + k] = (f16)(vf[c] - (float)hi);
            }
        }
        __syncthreads();

        f16x8 ah[2], al[2], bh[4], bl[4];
#pragma unroll
        for (int m = 0; m < 2; ++m) {
            ah[m] = *(const f16x8*)(&xh[(wv * 32 + m * 16 + lr) * 40 + kg * 8]);
            al[m] = *(const f16x8*)(&xl[(wv * 32 + m * 16 + lr) * 40 + kg * 8]);
        }
#pragma unroll
        for (int n = 0; n < 4; ++n) {
            bh[n] = *(const f16x8*)(&wth[(n * 16 + lr) * 40 + kg * 8]);
            bl[n] = *(const f16x8*)(&wtl[(n * 16 + lr) * 40 + kg * 8]);
        }
#pragma unroll
        for (int m = 0; m < 2; ++m)
#pragma unroll
            for (int n = 0; n < 4; ++n) {
                acc[m][n] = __builtin_amdgcn_mfma_f32_16x16x32_f16(ah[m], bh[n], acc[m][n], 0, 0, 0);
                acc[m][n] = __builtin_amdgcn_mfma_f32_16x16x32_f16(ah[m], bl[n], acc[m][n], 0, 0, 0);
                acc[m][n] = __builtin_amdgcn_mfma_f32_16x16x32_f16(al[m], bh[n], acc[m][n], 0, 0, 0);
            }
        __syncthreads();
    }

    // epilogue: LDS transpose, coalesced 16 B stores (unscaled)
    f16* ob = (f16*)lds_raw;               // [128][72] halves
#pragma unroll
    for (int m = 0; m < 2; ++m) {
#pragma unroll
        for (int r = 0; r < 4; ++r) {
            int rl = wv * 32 + m * 16 + kg * 4 + r;
#pragma unroll
            for (int n = 0; n < 4; ++n)
                ob[rl * 72 + n * 16 + lr] = (f16)(acc[m][n][r]);
        }
    }
    __syncthreads();
#pragma unroll
    for (int i = 0; i < 4; ++i) {
        int L = i * 256 + t;
        int r = L >> 3;
        int sg = L & 7;
        int rg = row0 + r;
        if (rg < N_NODES) {
            f16x8 v = *(const f16x8*)(&ob[r * 72 + sg * 8]);
            *(f16x8*)(s1h + (size_t)rg * HID + sg * 8) = v;
        }
    }
}

__global__ __launch_bounds__(256) void fused_pg(const int* __restrict__ row,
                                                const int* __restrict__ col,
                                                int* __restrict__ gcur,
                                                int* __restrict__ part,
                                                const float* __restrict__ x,
                                                const float* __restrict__ W1,
                                                __half* __restrict__ s1h) {
    __shared__ __align__(16) char smem[30720];
    const int bid = blockIdx.x;
    if (bid & 1) gemm1_body(bid >> 1, x, W1, s1h, smem);
    else         partition_body(bid >> 1, row, col, gcur, part, smem);
}

// ================= tail_fused (r27): build | gridsync | gather1 | gridsync | gather2
// Merges 3 launches into 1 cooperative kernel (launch overhead ~15-20 us each,
// inferred from r0/r22/r26 kernel-sum vs total accounting). Build phase upgraded
// to 8 per-wave private histograms (stride 132 to decorrelate banks): removes
// ~8x same-address LDS-atomic serialization on the 128 node counters (mean 32
// hits/counter) in both hist and scatter passes.
__global__ __launch_bounds__(512, 6) void tail_fused(
        const int* __restrict__ gcur, const int* __restrict__ part,
        int* __restrict__ ptrb, int* __restrict__ ptre,
        float* __restrict__ dis, int* __restrict__ srcs,
        __half* __restrict__ s1h, __half* __restrict__ s2h,
        const float* __restrict__ b1, const float* __restrict__ W2,
        const float* __restrict__ b2, const float* __restrict__ Wc,
        const float* __restrict__ bc, float* __restrict__ out) {
    __shared__ __align__(16) char sm[27776];
    // build-phase layout
    int*   pcache = (int*)sm;               // CAP ints        (18432 B)
    int*   wh     = (int*)(sm + 18432);     // [8][132] ints   (4224 B)
    int*   wpre   = (int*)(sm + 22656);     // [8][128] ints   (4096 B)
    int*   lsm    = (int*)(sm + 26752);     // [128] ints      (512 B)
    float* ldis   = (float*)(sm + 27264);   // [128] floats    (512 B)
    // gather-phase alias
    float* w2lds  = (float*)sm;             // HID*OUTC floats (8192 B)
    float* hbuf   = (float*)(sm + 8192);    // [8][HID] floats (2048 B)

    const int t  = threadIdx.x;
    const int wv = t >> 6;                  // wave 0..7
    const int j  = t & 63;                  // lane

    // ---------------- phase 1: bucket build (+ dis + s1h rescale) ----------------
    for (int b = blockIdx.x; b < NBUCK; b += gridDim.x) {
        const int cnt = gcur[b];            // relative count (gcur zeroed pre-launch)
        const size_t pbase = (size_t)b * CAP;

        for (int i = t; i < 8 * 132; i += 512) wh[i] = 0;
        __syncthreads();

        for (int i = t; i < cnt; i += 512) {
            int p = part[pbase + i];
            pcache[i] = p;
            atomicAdd(&wh[wv * 132 + (p >> 17)], 1);   // per-wave private hist
        }
        __syncthreads();

        int val = 0, lbv = 0;
        if (t < BNODES) {
            int s = 0;
#pragma unroll
            for (int q = 0; q < 8; ++q) { wpre[q * 128 + t] = s; s += wh[q * 132 + t]; }
            val = s;
            lsm[t] = s;
        }
        __syncthreads();
        for (int off = 1; off < BNODES; off <<= 1) {
            int add = (t >= off && t < BNODES) ? lsm[t - off] : 0;
            __syncthreads();
            if (t < BNODES) lsm[t] += add;
            __syncthreads();
        }
        if (t < BNODES) {
            lbv = lsm[t] - val;             // exclusive scan
            float d = rsqrtf((float)val + 1.0f);   // +1 self-loop
            ldis[t] = d;
            int v = b * BNODES + t;
            if (v < N_NODES) {
                ptrb[v] = b * CAP + lbv;
                ptre[v] = b * CAP + lbv + val;
                dis[v]  = d;
            }
#pragma unroll
            for (int q = 0; q < 8; ++q) wh[q * 132 + t] = lbv + wpre[q * 128 + t]; // cursors
        }
        __syncthreads();

        for (int i = t; i < cnt; i += 512) {
            int p    = pcache[i];
            int dlow = p >> 17;
            int r    = atomicAdd(&wh[wv * 132 + dlow], 1);   // per-wave cursor
            srcs[pbase + r] = p & 0x1FFFF;
        }

        // rescale this bucket's s1h rows by dis (restores s1h[n]=dis[n]*(x@W1)[n])
        {
            int base_node = b * BNODES;
            int nrows = N_NODES - base_node;
            if (nrows > BNODES) nrows = BNODES;
            int nwork = nrows * 8;
            for (int i = t; i < nwork; i += 512) {
                int r  = i >> 3;
                int sg = i & 7;
                f16x8* pp = (f16x8*)(s1h + (size_t)(base_node + r) * HID + sg * 8);
                f16x8 vv = *pp;
                float d = ldis[r];
                f16x8 ov;
#pragma unroll
                for (int c = 0; c < 8; ++c) ov[c] = (f16)((float)vv[c] * d);
                *pp = ov;
            }
        }
        __syncthreads();
    }

    __threadfence();
    cg::this_grid().sync();

    // ---------------- phase 2: gather1 + ELU + fused gemm2 ----------------------
    {
        const float4* s4 = (const float4*)W2;
        if (t < 512) ((float4*)w2lds)[t] = s4[t];   // 8 KB
    }
    __syncthreads();

    {
        const int l = j & 31;
        const int h = j >> 5;
        const __half2* s12 = (const __half2*)s1h;
        const int nw = gridDim.x * 8;
        for (int vv = blockIdx.x * 8 + wv; vv < N_NODES; vv += nw) {
            const int v = __builtin_amdgcn_readfirstlane(vv);
            float2 acc;
            {
                float2 self = __half22float2(s12[(v << 5) | l]);
                acc = (h == 0) ? self : make_float2(0.f, 0.f);
            }
            const int beg = ptrb[v];
            const int end = ptre[v];

            for (int base = beg; base < end; base += 64) {
                int mysrc = 0;
                if (base + j < end) mysrc = srcs[base + j];
                int nk = end - base;
                if (nk > 64) nk = 64;
                const int full = nk >> 1;
                int i = 0;
                for (; i + 8 <= full; i += 8) {
                    int s  = 2 * i + h;
                    int a0 = __shfl(mysrc, s,      64);
                    int a1 = __shfl(mysrc, s + 2,  64);
                    int a2 = __shfl(mysrc, s + 4,  64);
                    int a3 = __shfl(mysrc, s + 6,  64);
                    int a4 = __shfl(mysrc, s + 8,  64);
                    int a5 = __shfl(mysrc, s + 10, 64);
                    int a6 = __shfl(mysrc, s + 12, 64);
                    int a7 = __shfl(mysrc, s + 14, 64);
                    float2 g0 = __half22float2(s12[(a0 << 5) | l]);
                    float2 g1 = __half22float2(s12[(a1 << 5) | l]);
                    float2 g2 = __half22float2(s12[(a2 << 5) | l]);
                    float2 g3 = __half22float2(s12[(a3 << 5) | l]);
                    float2 g4 = __half22float2(s12[(a4 << 5) | l]);
                    float2 g5 = __half22float2(s12[(a5 << 5) | l]);
                    float2 g6 = __half22float2(s12[(a6 << 5) | l]);
                    float2 g7 = __half22float2(s12[(a7 << 5) | l]);
                    acc.x += ((g0.x + g1.x) + (g2.x + g3.x)) + ((g4.x + g5.x) + (g6.x + g7.x));
                    acc.y += ((g0.y + g1.y) + (g2.y + g3.y)) + ((g4.y + g5.y) + (g6.y + g7.y));
                }
                if (2 * i < nk) {
                    const int last = nk - 1;
#pragma unroll
                    for (int u = 0; u < 8; ++u) {
                        int s  = 2 * (i + u) + h;
                        int sc = s < last ? s : last;
                        int a  = __shfl(mysrc, sc, 64);
                        float wgt = (s < nk) ? 1.f : 0.f;
                        float2 g = __half22float2(s12[(a << 5) | l]);
                        acc.x = fmaf(wgt, g.x, acc.x);
                        acc.y = fmaf(wgt, g.y, acc.y);
                    }
                }
            }
            acc.x += __shfl_xor(acc.x, 32, 64);
            acc.y += __shfl_xor(acc.y, 32, 64);

            float dv = dis[v];
            float2 bb = *(const float2*)(b1 + 2 * l);
            float t0 = dv * acc.x + bb.x;
            float t1 = dv * acc.y + bb.y;
            float h0 = t0 > 0.f ? t0 : (expf(t0) - 1.f);
            float h1 = t1 > 0.f ? t1 : (expf(t1) - 1.f);
            if (h == 0) {
                hbuf[wv * HID + 2 * l]     = h0;
                hbuf[wv * HID + 2 * l + 1] = h1;
            }

            const int jo = j & 31;
            const int kb = (j >> 5) * 32;
            float p = 0.f;
#pragma unroll
            for (int kk = 0; kk < 32; ++kk)
                p += hbuf[wv * HID + kb + kk] * w2lds[(kb + kk) * OUTC + jo];
            p += __shfl_xor(p, 32, 64);
            if (j < 32) {
                s2h[(size_t)v * OUTC + jo] = __float2half(dv * p);
            }
        }
    }

    __threadfence();
    cg::this_grid().sync();

    // ---------------- phase 3: gather2 + ELU + final projection -----------------
    {
        const int l = j & 3;
        const int e = j >> 2;
        const float4* s24 = (const float4*)s2h;
        const int nw = gridDim.x * 8;
        for (int vv = blockIdx.x * 8 + wv; vv < N_NODES; vv += nw) {
            const int v = __builtin_amdgcn_readfirstlane(vv);
            float acc[8] = {0.f, 0.f, 0.f, 0.f, 0.f, 0.f, 0.f, 0.f};
            if (e == 0) acc8(acc, s24[(v << 2) | l]);

            const int beg = ptrb[v];
            const int end = ptre[v];
            for (int base = beg; base < end; base += 64) {
                int mys = 0;
                if (base + j < end) mys = srcs[base + j];
                int nk = end - base;
                if (nk > 64) nk = 64;
                int off = 0;
                for (; off + 32 <= nk; off += 32) {
                    int a0 = __shfl(mys, off + e,      64);
                    int a1 = __shfl(mys, off + 16 + e, 64);
                    float4 r0 = s24[(a0 << 2) | l];
                    float4 r1 = s24[(a1 << 2) | l];
                    acc8(acc, r0);
                    acc8(acc, r1);
                }
                if (off < nk) {
                    const int last = nk - 1;
                    int s0 = off + e, s1 = off + 16 + e;
                    int a0 = __shfl(mys, s0 < last ? s0 : last, 64);
                    int a1 = __shfl(mys, s1 < last ? s1 : last, 64);
                    if (s0 < nk) acc8(acc, s24[(a0 << 2) | l]);
                    if (s1 < nk) acc8(acc, s24[(a1 << 2) | l]);
                }
            }
#pragma unroll
            for (int i = 0; i < 8; ++i) {
                acc[i] += __shfl_xor(acc[i], 4, 64);
                acc[i] += __shfl_xor(acc[i], 8, 64);
                acc[i] += __shfl_xor(acc[i], 16, 64);
                acc[i] += __shfl_xor(acc[i], 32, 64);
            }

            float dv = dis[v];
            float4 ba = ((const float4*)b2)[2 * l];
            float4 bb = ((const float4*)b2)[2 * l + 1];
            float4 wa = ((const float4*)Wc)[2 * l];
            float4 wb = ((const float4*)Wc)[2 * l + 1];
            const float* bf = (const float*)&ba;
            const float* bg = (const float*)&bb;
            const float* wf = (const float*)&wa;
            const float* wg = (const float*)&wb;
            float p = 0.f;
#pragma unroll
            for (int i = 0; i < 8; ++i) {
                float bias = (i < 4) ? bf[i] : bg[i - 4];
                float wc   = (i < 4) ? wf[i] : wg[i - 4];
                float tt = dv * acc[i] + bias;
                float hh = tt > 0.f ? tt : (expf(tt) - 1.f);
                p += hh * wc;
            }
            p += __shfl_xor(p, 1, 64);
            p += __shfl_xor(p, 2, 64);
            if (j == 0) out[v] = p + bc[0];
        }
    }
}

extern "C" void kernel_launch(void* const* d_in, const int* in_sizes, int n_in,
                              void* d_out, int out_size, void* d_ws, size_t ws_size,
                              hipStream_t stream) {
    const float* x  = (const float*)d_in[0];
    const int*   ei = (const int*)d_in[1];
    const float* W1 = (const float*)d_in[2];
    const float* b1 = (const float*)d_in[3];
    const float* W2 = (const float*)d_in[4];
    const float* b2 = (const float*)d_in[5];
    const float* Wc = (const float*)d_in[6];
    const float* bc = (const float*)d_in[7];
    float* out = (float*)d_out;

    const int* row = ei;            // edge_index[0] = source
    const int* col = ei + N_EDGES;  // edge_index[1] = target

    char* ws = (char*)d_ws;
    int*    ptrb = (int*)   (ws + OFF_PTRB);
    int*    ptre = (int*)   (ws + OFF_PTRE);
    int*    gcur = (int*)   (ws + OFF_GCUR);
    float*  dis  = (float*) (ws + OFF_DIS);
    int*    srcs = (int*)   (ws + OFF_SRC);
    int*    part = (int*)   (ws + OFF_PART);
    __half* s1h  = (__half*)(ws + OFF_S1);
    __half* s2h  = (__half*)(ws + OFF_S2);

    hipMemsetAsync(gcur, 0, (size_t)NBUCK * 4, stream);
    fused_pg<<<NPART + NG1, 256, 0, stream>>>(row, col, gcur, part, x, W1, s1h);

    static int coop_blocks = 0;
    if (coop_blocks == 0) {
        int maxb = 0;
        hipOccupancyMaxActiveBlocksPerMultiprocessor(&maxb, tail_fused, 512, 0);
        if (maxb < 1) maxb = 1;
        coop_blocks = maxb * 256;
        if (coop_blocks > 1024) coop_blocks = 1024;
    }
    void* kargs[] = { (void*)&gcur, (void*)&part, (void*)&ptrb, (void*)&ptre,
                      (void*)&dis,  (void*)&srcs, (void*)&s1h,  (void*)&s2h,
                      (void*)&b1,   (void*)&W2,   (void*)&b2,   (void*)&Wc,
                      (void*)&bc,   (void*)&out };
    hipLaunchCooperativeKernel((void*)tail_fused, dim3(coop_blocks), dim3(512),
                               kargs, 0, stream);
}

// Round 11
// 363.138 us; speedup vs baseline: 2.0795x; 2.0795x over previous
//
#include <hip/hip_runtime.h>
#include <hip/hip_fp16.h>
#include <math.h>

#define N_NODES 100000
#define N_EDGES 3200000
#define IN_CH   256
#define HID     64
#define OUTC    32
#define BSHIFT  7                         // 128-node buckets -> 782 build blocks (~3/CU)
#define BNODES  128
#define NBUCK   ((N_NODES + BNODES - 1) / BNODES)   // 782 buckets
#define CHUNK   4096                      // edges per partition block
#define EPT     16                        // edges per thread (CHUNK/256)
#define CAP     4608                      // bucket capacity: mean 4092 + ~8 sigma
#define NPART   ((N_EDGES + CHUNK - 1) / CHUNK)     // 782 partition blocks
#define NG1     ((N_NODES + 127) / 128)             // 782 gemm1 blocks

// ---------------- workspace layout (bytes) ----------------
// s1h does NOT alias part — partition (writes part) and gemm1 (writes s1h)
// run CONCURRENTLY in fused_pg. ~50 MB total.
static constexpr size_t align256(size_t x) { return (x + 255) & ~(size_t)255; }
static constexpr size_t OFF_PTRB = 0;                                          // N ints
static constexpr size_t OFF_PTRE = OFF_PTRB + align256((size_t)N_NODES * 4);   // N ints
static constexpr size_t OFF_GCUR = OFF_PTRE + align256((size_t)N_NODES * 4);   // NBUCK ints (memset 0)
static constexpr size_t OFF_DIS  = OFF_GCUR + align256((size_t)NBUCK * 4);     // N floats
static constexpr size_t OFF_SRC  = OFF_DIS  + align256((size_t)N_NODES * 4);   // NBUCK*CAP ints
static constexpr size_t OFF_PART = OFF_SRC  + align256((size_t)NBUCK * CAP * 4); // NBUCK*CAP ints (14.4 MB)
static constexpr size_t OFF_S1   = OFF_PART + align256((size_t)NBUCK * CAP * 4); // N*64 halves (12.8 MB)
static constexpr size_t OFF_S2   = OFF_S1   + align256((size_t)N_NODES * HID * 2); // N*32 halves (6.4 MB)

typedef _Float16 f16;
typedef f16 f16x8 __attribute__((ext_vector_type(8)));
typedef float f32x4 __attribute__((ext_vector_type(4)));

// unpack one 16 B chunk (8 halves) and accumulate into 8 fp32 accumulators
__device__ __forceinline__ void acc8(float* acc, float4 raw) {
    const __half2* hp = (const __half2*)&raw;
    float2 f0 = __half22float2(hp[0]);
    float2 f1 = __half22float2(hp[1]);
    float2 f2 = __half22float2(hp[2]);
    float2 f3 = __half22float2(hp[3]);
    acc[0] += f0.x; acc[1] += f0.y; acc[2] += f1.x; acc[3] += f1.y;
    acc[4] += f2.x; acc[5] += f2.y; acc[6] += f3.x; acc[7] += f3.y;
}

// ================= FUSED partition + gemm1 ==================================
// Even blocks: partition body (782). Odd blocks: gemm1 body (782). Independent
// because s1h stores UNSCALED x@W1; the dis scale is applied by bucket_build.
// r27's cooperative 3-phase tail measured 843 us (5x regression) — launch
// overhead is cheaper than cooperative grid sync on this machine. Reverted.

__device__ __forceinline__ void partition_body(int pb, const int* __restrict__ row,
                                               const int* __restrict__ col,
                                               int* __restrict__ gcur,
                                               int* __restrict__ part,
                                               char* smem) {
    int* lhist = (int*)smem;            // NBUCK ints (3128 B)
    int* lbase = lhist + NBUCK;         // NBUCK ints (relative base in bucket)
    const int t  = threadIdx.x;
    const int e0 = pb * CHUNK;
    for (int i = t; i < NBUCK; i += 256) lhist[i] = 0;
    __syncthreads();

    int pk[EPT], br[EPT];
#pragma unroll
    for (int i = 0; i < EPT; ++i) {
        int e = e0 + i * 256 + t;
        if (e < N_EDGES) {
            int d = col[e];
            int b = d >> BSHIFT;
            int r = atomicAdd(&lhist[b], 1);
            pk[i] = row[e] | ((d & (BNODES - 1)) << 17);   // 17+7=24 bits
            br[i] = b | (r << 10);           // b<1024, r<4096 -> fits
        } else {
            br[i] = -1;
        }
    }
    __syncthreads();

    const int off = (int)((pb * 131u) % NBUCK);
    for (int i = t; i < NBUCK; i += 256) {
        int bb = i + off;
        if (bb >= NBUCK) bb -= NBUCK;
        int c = lhist[bb];
        lbase[bb] = (c > 0) ? atomicAdd(&gcur[bb], c) : 0;   // RELATIVE base (gcur zeroed)
    }
    __syncthreads();

#pragma unroll
    for (int i = 0; i < EPT; ++i) {
        if (br[i] >= 0) {
            int b = br[i] & 1023;
            int r = br[i] >> 10;
            part[b * CAP + lbase[b] + r] = pk[i];
        }
    }
}

// gemm1 body: s1h[n][j] = fp16(x[n,:] @ W1[:,j])   (UNSCALED)
// Split-fp16 (x=xh+xl, W=wh+wl; S ~= xh*wh + xh*wl + xl*wh, err ~2^-22 rel).
__device__ __forceinline__ void gemm1_body(int gb, const float* __restrict__ x,
                                           const float* __restrict__ W1,
                                           __half* __restrict__ s1h,
                                           char* lds_raw) {
    f16* xh  = (f16*)lds_raw;              // [128][40] halves, 10240 B
    f16* xl  = (f16*)(lds_raw + 10240);    // [128][40] halves, 10240 B
    f16* wth = (f16*)(lds_raw + 20480);    // [64][40] halves: W^T hi chunk, 5120 B
    f16* wtl = (f16*)(lds_raw + 25600);    // [64][40] halves: W^T lo chunk, 5120 B

    const int t    = threadIdx.x;
    const int row0 = gb * 128;
    const int lane = t & 63;
    const int wv   = t >> 6;               // wave 0..3 owns rows wv*32..wv*32+31
    const int lr   = lane & 15;            // A row / B col within 16-tile
    const int kg   = lane >> 4;            // k-group: k = kg*8..kg*8+7

    f32x4 acc[2][4];
#pragma unroll
    for (int m = 0; m < 2; ++m)
#pragma unroll
        for (int n = 0; n < 4; ++n) acc[m][n] = (f32x4){0.f, 0.f, 0.f, 0.f};

    for (int kt = 0; kt < 8; ++kt) {
#pragma unroll
        for (int i = 0; i < 4; ++i) {
            int L  = i * 256 + t;          // 0..1023 = 128 rows x 8 float4
            int r  = L >> 3;
            int k4 = L & 7;
            int rg = row0 + r;
            float4 v = make_float4(0.f, 0.f, 0.f, 0.f);
            if (rg < N_NODES)
                v = ((const float4*)x)[(size_t)rg * 64 + kt * 8 + k4];
            union { f16 h[4]; unsigned long long u; } ph, pl;
            const float* vf = (const float*)&v;
#pragma unroll
            for (int c = 0; c < 4; ++c) {
                f16 hi = (f16)vf[c];
                ph.h[c] = hi;
                pl.h[c] = (f16)(vf[c] - (float)hi);
            }
            *(unsigned long long*)(&xh[r * 40 + k4 * 4]) = ph.u;
            *(unsigned long long*)(&xl[r * 40 + k4 * 4]) = pl.u;
        }
#pragma unroll
        for (int i = 0; i < 2; ++i) {
            int L  = i * 256 + t;          // 0..511 = 32 k x 16 float4
            int k  = L >> 4;
            int j4 = L & 15;
            float4 v = ((const float4*)W1)[(size_t)(kt * 32 + k) * 16 + j4];
            const float* vf = (const float*)&v;
#pragma unroll
            for (int c = 0; c < 4; ++c) {
                f16 hi = (f16)vf[c];
                wth[(j4 * 4 + c) * 40 + k] = hi;
                wtl[(j4 * 4 + c) * 40 + k] = (f16)(vf[c] - (float)hi);
            }
        }
        __syncthreads();

        f16x8 ah[2], al[2], bh[4], bl[4];
#pragma unroll
        for (int m = 0; m < 2; ++m) {
            ah[m] = *(const f16x8*)(&xh[(wv * 32 + m * 16 + lr) * 40 + kg * 8]);
            al[m] = *(const f16x8*)(&xl[(wv * 32 + m * 16 + lr) * 40 + kg * 8]);
        }
#pragma unroll
        for (int n = 0; n < 4; ++n) {
            bh[n] = *(const f16x8*)(&wth[(n * 16 + lr) * 40 + kg * 8]);
            bl[n] = *(const f16x8*)(&wtl[(n * 16 + lr) * 40 + kg * 8]);
        }
#pragma unroll
        for (int m = 0; m < 2; ++m)
#pragma unroll
            for (int n = 0; n < 4; ++n) {
                acc[m][n] = __builtin_amdgcn_mfma_f32_16x16x32_f16(ah[m], bh[n], acc[m][n], 0, 0, 0);
                acc[m][n] = __builtin_amdgcn_mfma_f32_16x16x32_f16(ah[m], bl[n], acc[m][n], 0, 0, 0);
                acc[m][n] = __builtin_amdgcn_mfma_f32_16x16x32_f16(al[m], bh[n], acc[m][n], 0, 0, 0);
            }
        __syncthreads();
    }

    // epilogue: LDS transpose, coalesced 16 B stores (no dis scale)
    // C/D layout: col = lane&15, row = (lane>>4)*4 + reg  [m89-verified]
    f16* ob = (f16*)lds_raw;               // [128][72] halves = 18432 B
#pragma unroll
    for (int m = 0; m < 2; ++m) {
#pragma unroll
        for (int r = 0; r < 4; ++r) {
            int rl = wv * 32 + m * 16 + kg * 4 + r;
#pragma unroll
            for (int n = 0; n < 4; ++n)
                ob[rl * 72 + n * 16 + lr] = (f16)(acc[m][n][r]);
        }
    }
    __syncthreads();
#pragma unroll
    for (int i = 0; i < 4; ++i) {
        int L = i * 256 + t;               // 0..1023 = 128 rows x 8 segs of 8 halves
        int r = L >> 3;
        int sg = L & 7;
        int rg = row0 + r;
        if (rg < N_NODES) {
            f16x8 v = *(const f16x8*)(&ob[r * 72 + sg * 8]);
            *(f16x8*)(s1h + (size_t)rg * HID + sg * 8) = v;
        }
    }
}

__global__ __launch_bounds__(256) void fused_pg(const int* __restrict__ row,
                                                const int* __restrict__ col,
                                                int* __restrict__ gcur,
                                                int* __restrict__ part,
                                                const float* __restrict__ x,
                                                const float* __restrict__ W1,
                                                __half* __restrict__ s1h) {
    __shared__ __align__(16) char smem[30720];
    const int bid = blockIdx.x;
    if (bid & 1) gemm1_body(bid >> 1, x, W1, s1h, smem);
    else         partition_body(bid >> 1, row, col, gcur, part, smem);
}

// ---------------- bucket_build: 782 blocks x 512 threads -------------------------
// After computing dis for its 128 nodes, each block also RESCALES the s1h rows
// it owns (s1h[n] *= dis[n]; 25.6 MB streamed, coalesced). This restores the
// invariant s1h[n] = dis[n]*(x@W1)[n] so gather1 keeps its measured-best
// pure-sum shape with no per-edge dis loads.
__global__ __launch_bounds__(512) void bucket_build(const int* __restrict__ gcur,
                                                    const int* __restrict__ part,
                                                    int* __restrict__ ptrb,
                                                    int* __restrict__ ptre,
                                                    float* __restrict__ dis,
                                                    int* __restrict__ srcs,
                                                    __half* __restrict__ s1h) {
    __shared__ int pcache[CAP];    // 18432 B: this bucket's packed edges
    __shared__ int lh[BNODES];     // per-node count
    __shared__ int lb[BNODES];     // exclusive scan (bucket-local base)
    __shared__ int lcur[BNODES];   // fill cursor
    __shared__ int ls[BNODES];
    __shared__ float ldis[BNODES]; // dis for this bucket's nodes
    const int b = blockIdx.x;
    const int t = threadIdx.x;
    if (t < BNODES) { lh[t] = 0; lcur[t] = 0; }
    __syncthreads();
    const int cnt = gcur[b];                 // relative count (gcur zeroed)
    const size_t pbase = (size_t)b * CAP;

    for (int i = t; i < cnt; i += 512) {
        int p = part[pbase + i];
        pcache[i] = p;
        atomicAdd(&lh[p >> 17], 1);
    }
    __syncthreads();

    int val = (t < BNODES) ? lh[t] : 0;
    if (t < BNODES) ls[t] = val;
    __syncthreads();
    for (int off = 1; off < BNODES; off <<= 1) {
        int add = (t >= off && t < BNODES) ? ls[t - off] : 0;
        __syncthreads();
        if (t < BNODES) ls[t] += add;
        __syncthreads();
    }
    if (t < BNODES) lb[t] = ls[t] - val;   // exclusive
    __syncthreads();

    int v = b * BNODES + t;
    if (t < BNODES) {
        float d = rsqrtf((float)val + 1.0f);   // +1 self-loop
        ldis[t] = d;
        if (v < N_NODES) {
            ptrb[v] = b * CAP + lb[t];
            ptre[v] = b * CAP + lb[t] + val;
            dis[v]  = d;
        }
    }
    __syncthreads();

    // scatter into srcs
    for (int i = t; i < cnt; i += 512) {
        int p    = pcache[i];
        int dlow = p >> 17;
        int src  = p & 0x1FFFF;
        int r    = atomicAdd(&lcur[dlow], 1);
        srcs[pbase + lb[dlow] + r] = src;
    }

    // rescale this bucket's s1h rows by dis (coalesced 16 B ops)
    {
        int nrows = N_NODES - b * BNODES;
        if (nrows > BNODES) nrows = BNODES;
        const int nwork = nrows * 8;           // 8 f16x8 segs per 64-half row
        for (int i = t; i < nwork; i += 512) {
            int r  = i >> 3;
            int sg = i & 7;
            __half* p = s1h + (size_t)(b * BNODES + r) * HID + sg * 8;
            f16x8 vv = *(const f16x8*)p;
            float d = ldis[r];
            f16x8 ov;
#pragma unroll
            for (int c = 0; c < 8; ++c) ov[c] = (f16)((float)vv[c] * d);
            *(f16x8*)p = ov;
        }
    }
}

// ---------------- gather1 + ELU + fused GEMM2 (measured-best shape) ---------------
// s1h rows pre-scaled by dis[src] (bucket_build). One coalesced srcs load per
// 64-edge block, __shfl broadcast, 8 gathers in flight.
__global__ __launch_bounds__(256) void gather1(const __half* __restrict__ s1h,
                                               const int* __restrict__ ptrb,
                                               const int* __restrict__ ptre,
                                               const int* __restrict__ srcs,
                                               const float* __restrict__ dis,
                                               const float* __restrict__ b1,
                                               const float* __restrict__ W2,
                                               __half* __restrict__ s2h) {
    __shared__ float w2lds[HID * OUTC];   // 8 KB: [k][jo]
    __shared__ float hbuf[4][HID];        // per-wave ELU'd h row

    const int t = threadIdx.x;
    {
        float4* l4 = (float4*)w2lds;
        const float4* s4 = (const float4*)W2;
        l4[t] = s4[t];
        l4[256 + t] = s4[256 + t];
    }
    __syncthreads();

    const int j = t & 63;
    const int w = t >> 6;
    const int l = j & 31;                 // half2 index within row (features 2l,2l+1)
    const int h = j >> 5;                 // edge-of-pair selector
    const int v = __builtin_amdgcn_readfirstlane(blockIdx.x * 4 + w);
    const __half2* s12 = (const __half2*)s1h;   // row stride 32 half2

    float2 acc;
    {
        float2 self = __half22float2(s12[(v << 5) | l]);
        acc = (h == 0) ? self : make_float2(0.f, 0.f);   // self-loop counted once
    }
    const int beg = ptrb[v];
    const int end = ptre[v];

    for (int base = beg; base < end; base += 64) {
        int mysrc = 0;
        if (base + j < end) mysrc = srcs[base + j];   // one coalesced load / 64 edges
        int nk = end - base;
        if (nk > 64) nk = 64;
        const int full = nk >> 1;                     // complete pairs
        int i = 0;
        // unmasked 8-pair (16-edge) blocks: 8 gathers in flight, no tail logic
        for (; i + 8 <= full; i += 8) {
            int s  = 2 * i + h;
            int a0 = __shfl(mysrc, s,      64);
            int a1 = __shfl(mysrc, s + 2,  64);
            int a2 = __shfl(mysrc, s + 4,  64);
            int a3 = __shfl(mysrc, s + 6,  64);
            int a4 = __shfl(mysrc, s + 8,  64);
            int a5 = __shfl(mysrc, s + 10, 64);
            int a6 = __shfl(mysrc, s + 12, 64);
            int a7 = __shfl(mysrc, s + 14, 64);
            float2 g0 = __half22float2(s12[(a0 << 5) | l]);
            float2 g1 = __half22float2(s12[(a1 << 5) | l]);
            float2 g2 = __half22float2(s12[(a2 << 5) | l]);
            float2 g3 = __half22float2(s12[(a3 << 5) | l]);
            float2 g4 = __half22float2(s12[(a4 << 5) | l]);
            float2 g5 = __half22float2(s12[(a5 << 5) | l]);
            float2 g6 = __half22float2(s12[(a6 << 5) | l]);
            float2 g7 = __half22float2(s12[(a7 << 5) | l]);
            acc.x += ((g0.x + g1.x) + (g2.x + g3.x)) + ((g4.x + g5.x) + (g6.x + g7.x));
            acc.y += ((g0.y + g1.y) + (g2.y + g3.y)) + ((g4.y + g5.y) + (g6.y + g7.y));
        }
        // one masked 8-pair block covers the remaining <=15 slots (incl. odd edge)
        if (2 * i < nk) {
            const int last = nk - 1;
#pragma unroll
            for (int u = 0; u < 8; ++u) {
                int s  = 2 * (i + u) + h;
                int sc = s < last ? s : last;
                int a  = __shfl(mysrc, sc, 64);
                float wgt = (s < nk) ? 1.f : 0.f;
                float2 g = __half22float2(s12[(a << 5) | l]);
                acc.x = fmaf(wgt, g.x, acc.x);
                acc.y = fmaf(wgt, g.y, acc.y);
            }
        }
    }
    acc.x += __shfl_xor(acc.x, 32, 64);   // even-edge + odd-edge partials
    acc.y += __shfl_xor(acc.y, 32, 64);

    float dv = dis[v];
    float2 bb = *(const float2*)(b1 + 2 * l);
    float t0 = dv * acc.x + bb.x;
    float t1 = dv * acc.y + bb.y;
    float h0 = t0 > 0.f ? t0 : (expf(t0) - 1.f);
    float h1 = t1 > 0.f ? t1 : (expf(t1) - 1.f);
    if (h == 0) {
        hbuf[w][2 * l]     = h0;
        hbuf[w][2 * l + 1] = h1;
    }

    // ---- fused gemm2: s2[v][jo] = dis[v] * sum_k hh[k] * W2[k][jo]
    const int jo = j & 31;
    const int kb = (j >> 5) * 32;          // lower lanes: k 0..31, upper: 32..63
    float p = 0.f;
#pragma unroll
    for (int kk = 0; kk < 32; ++kk)
        p += hbuf[w][kb + kk] * w2lds[(kb + kk) * OUTC + jo];
    p += __shfl_xor(p, 32, 64);            // combine the two k-halves
    if (j < 32) {
        s2h[(size_t)v * OUTC + jo] = __float2half(dv * p);
    }
}

// ---------------- gather2 + ELU + final projection --------------------------------
__global__ __launch_bounds__(256) void gather2(const __half* __restrict__ s2h,
                                               const int* __restrict__ ptrb,
                                               const int* __restrict__ ptre,
                                               const int* __restrict__ srcs,
                                               const float* __restrict__ dis,
                                               const float* __restrict__ b2,
                                               const float* __restrict__ Wc,
                                               const float* __restrict__ bc,
                                               float* __restrict__ out) {
    const int j = threadIdx.x & 63;
    const int w = threadIdx.x >> 6;
    const int l = j & 3;                  // feature octet within row
    const int e = j >> 2;                 // edge-of-16 (0..15)
    const int v = __builtin_amdgcn_readfirstlane(blockIdx.x * 4 + w);
    const float4* s24 = (const float4*)s2h;   // row stride 4 float4s (64 B)

    float acc[8] = {0.f, 0.f, 0.f, 0.f, 0.f, 0.f, 0.f, 0.f};
    if (e == 0) acc8(acc, s24[(v << 2) | l]);   // self-loop

    const int beg = ptrb[v];
    const int end = ptre[v];
    for (int base = beg; base < end; base += 64) {
        int mys = 0;
        if (base + j < end) mys = srcs[base + j];
        int nk = end - base;
        if (nk > 64) nk = 64;
        int off = 0;
        for (; off + 32 <= nk; off += 32) {          // unmasked 32-edge blocks
            int a0 = __shfl(mys, off + e,      64);
            int a1 = __shfl(mys, off + 16 + e, 64);
            float4 r0 = s24[(a0 << 2) | l];
            float4 r1 = s24[(a1 << 2) | l];
            acc8(acc, r0);
            acc8(acc, r1);
        }
        if (off < nk) {                               // masked tail (<=31 edges)
            const int last = nk - 1;
            int s0 = off + e, s1 = off + 16 + e;
            int a0 = __shfl(mys, s0 < last ? s0 : last, 64);
            int a1 = __shfl(mys, s1 < last ? s1 : last, 64);
            if (s0 < nk) acc8(acc, s24[(a0 << 2) | l]);
            if (s1 < nk) acc8(acc, s24[(a1 << 2) | l]);
        }
    }
#pragma unroll
    for (int i = 0; i < 8; ++i) {
        acc[i] += __shfl_xor(acc[i], 4, 64);
        acc[i] += __shfl_xor(acc[i], 8, 64);
        acc[i] += __shfl_xor(acc[i], 16, 64);
        acc[i] += __shfl_xor(acc[i], 32, 64);
    }

    float dv = dis[v];
    float4 ba = ((const float4*)b2)[2 * l];
    float4 bb = ((const float4*)b2)[2 * l + 1];
    float4 wa = ((const float4*)Wc)[2 * l];
    float4 wb = ((const float4*)Wc)[2 * l + 1];
    const float* bf = (const float*)&ba;
    const float* bg = (const float*)&bb;
    const float* wf = (const float*)&wa;
    const float* wg = (const float*)&wb;
    float p = 0.f;
#pragma unroll
    for (int i = 0; i < 8; ++i) {
        float bias = (i < 4) ? bf[i] : bg[i - 4];
        float wc   = (i < 4) ? wf[i] : wg[i - 4];
        float tt = dv * acc[i] + bias;
        float hh = tt > 0.f ? tt : (expf(tt) - 1.f);
        p += hh * wc;
    }
    p += __shfl_xor(p, 1, 64);   // reduce over the 4 feature-lanes
    p += __shfl_xor(p, 2, 64);
    if (j == 0) out[v] = p + bc[0];
}

extern "C" void kernel_launch(void* const* d_in, const int* in_sizes, int n_in,
                              void* d_out, int out_size, void* d_ws, size_t ws_size,
                              hipStream_t stream) {
    const float* x  = (const float*)d_in[0];
    const int*   ei = (const int*)d_in[1];
    const float* W1 = (const float*)d_in[2];
    const float* b1 = (const float*)d_in[3];
    const float* W2 = (const float*)d_in[4];
    const float* b2 = (const float*)d_in[5];
    const float* Wc = (const float*)d_in[6];
    const float* bc = (const float*)d_in[7];
    float* out = (float*)d_out;

    const int* row = ei;            // edge_index[0] = source
    const int* col = ei + N_EDGES;  // edge_index[1] = target

    char* ws = (char*)d_ws;
    int*    ptrb = (int*)   (ws + OFF_PTRB);
    int*    ptre = (int*)   (ws + OFF_PTRE);
    int*    gcur = (int*)   (ws + OFF_GCUR);
    float*  dis  = (float*) (ws + OFF_DIS);
    int*    srcs = (int*)   (ws + OFF_SRC);
    int*    part = (int*)   (ws + OFF_PART);
    __half* s1h  = (__half*)(ws + OFF_S1);
    __half* s2h  = (__half*)(ws + OFF_S2);

    hipMemsetAsync(gcur, 0, (size_t)NBUCK * 4, stream);
    fused_pg    <<<NPART + NG1, 256, 0, stream>>>(row, col, gcur, part, x, W1, s1h);
    bucket_build<<<NBUCK, 512, 0, stream>>>(gcur, part, ptrb, ptre, dis, srcs, s1h);

    gather1<<<N_NODES / 4, 256, 0, stream>>>(s1h, ptrb, ptre, srcs, dis, b1, W2, s2h);
    gather2<<<N_NODES / 4, 256, 0, stream>>>(s2h, ptrb, ptre, srcs, dis, b2, Wc, bc, out);
}

// Round 12
// 353.011 us; speedup vs baseline: 2.1392x; 1.0287x over previous
//
#include <hip/hip_runtime.h>
#include <hip/hip_fp16.h>
#include <math.h>

#define N_NODES 100000
#define N_EDGES 3200000
#define IN_CH   256
#define HID     64
#define OUTC    32
#define BSHIFT  7                         // 128-node buckets -> 782 build blocks (~3/CU)
#define BNODES  128
#define NBUCK   ((N_NODES + BNODES - 1) / BNODES)   // 782 buckets
#define CHUNK   4096                      // edges per partition block
#define EPT     16                        // edges per thread (CHUNK/256)
#define CAP     4608                      // bucket capacity: mean 4092 + ~8 sigma
#define NPART   ((N_EDGES + CHUNK - 1) / CHUNK)     // 782 partition blocks
#define NG1     ((N_NODES + 63) / 64)               // 1563 gemm1 blocks (r29: 64-row tile)

// ---------------- workspace layout (bytes) ----------------
// s1h does NOT alias part — partition (writes part) and gemm1 (writes s1h)
// run CONCURRENTLY in fused_pg. ~50 MB total.
static constexpr size_t align256(size_t x) { return (x + 255) & ~(size_t)255; }
static constexpr size_t OFF_PTRB = 0;                                          // N ints
static constexpr size_t OFF_PTRE = OFF_PTRB + align256((size_t)N_NODES * 4);   // N ints
static constexpr size_t OFF_GCUR = OFF_PTRE + align256((size_t)N_NODES * 4);   // NBUCK ints (memset 0)
static constexpr size_t OFF_DIS  = OFF_GCUR + align256((size_t)NBUCK * 4);     // N floats
static constexpr size_t OFF_SRC  = OFF_DIS  + align256((size_t)N_NODES * 4);   // NBUCK*CAP ints
static constexpr size_t OFF_PART = OFF_SRC  + align256((size_t)NBUCK * CAP * 4); // NBUCK*CAP ints (14.4 MB)
static constexpr size_t OFF_S1   = OFF_PART + align256((size_t)NBUCK * CAP * 4); // N*64 halves (12.8 MB)
static constexpr size_t OFF_S2   = OFF_S1   + align256((size_t)N_NODES * HID * 2); // N*32 halves (6.4 MB)

typedef _Float16 f16;
typedef f16 f16x8 __attribute__((ext_vector_type(8)));
typedef float f32x4 __attribute__((ext_vector_type(4)));

// unpack one 16 B chunk (8 halves) and accumulate into 8 fp32 accumulators
__device__ __forceinline__ void acc8(float* acc, float4 raw) {
    const __half2* hp = (const __half2*)&raw;
    float2 f0 = __half22float2(hp[0]);
    float2 f1 = __half22float2(hp[1]);
    float2 f2 = __half22float2(hp[2]);
    float2 f3 = __half22float2(hp[3]);
    acc[0] += f0.x; acc[1] += f0.y; acc[2] += f1.x; acc[3] += f1.y;
    acc[4] += f2.x; acc[5] += f2.y; acc[6] += f3.x; acc[7] += f3.y;
}

// ================= FUSED partition + gemm1 ==================================
// r29: gemm1 M-tile 128 -> 64 rows. LDS/block 30720 -> 20480 B. fused_pg was
// latency-bound (MFMA 3.8%, VALU 8.6%, HBM 17%) at Occupancy 31% (~2.5
// blocks/CU, LDS-limited). Smaller tile -> +1 resident block/CU and a finer
// dispatch tail (2346 blocks, 1:2 partition:gemm interleave). Per-row gemm
// arithmetic is BIT-IDENTICAL (same K-order); only block granularity changes.

__device__ __forceinline__ void partition_body(int pb, const int* __restrict__ row,
                                               const int* __restrict__ col,
                                               int* __restrict__ gcur,
                                               int* __restrict__ part,
                                               char* smem) {
    int* lhist = (int*)smem;            // NBUCK ints (3128 B)
    int* lbase = lhist + NBUCK;         // NBUCK ints (relative base in bucket)
    const int t  = threadIdx.x;
    const int e0 = pb * CHUNK;
    for (int i = t; i < NBUCK; i += 256) lhist[i] = 0;
    __syncthreads();

    int pk[EPT], br[EPT];
#pragma unroll
    for (int i = 0; i < EPT; ++i) {
        int e = e0 + i * 256 + t;
        if (e < N_EDGES) {
            int d = col[e];
            int b = d >> BSHIFT;
            int r = atomicAdd(&lhist[b], 1);
            pk[i] = row[e] | ((d & (BNODES - 1)) << 17);   // 17+7=24 bits
            br[i] = b | (r << 10);           // b<1024, r<4096 -> fits
        } else {
            br[i] = -1;
        }
    }
    __syncthreads();

    const int off = (int)((pb * 131u) % NBUCK);
    for (int i = t; i < NBUCK; i += 256) {
        int bb = i + off;
        if (bb >= NBUCK) bb -= NBUCK;
        int c = lhist[bb];
        lbase[bb] = (c > 0) ? atomicAdd(&gcur[bb], c) : 0;   // RELATIVE base (gcur zeroed)
    }
    __syncthreads();

#pragma unroll
    for (int i = 0; i < EPT; ++i) {
        if (br[i] >= 0) {
            int b = br[i] & 1023;
            int r = br[i] >> 10;
            part[b * CAP + lbase[b] + r] = pk[i];
        }
    }
}

// gemm1 body (r29, 64-row tile): s1h[n][j] = fp16(x[n,:] @ W1[:,j])  (UNSCALED)
// Split-fp16 (x=xh+xl, W=wh+wl; S ~= xh*wh + xh*wl + xl*wh, err ~2^-22 rel).
// Wave wv owns rows wv*16..wv*16+15 (one 16-row M-tile, 4 N-tiles).
__device__ __forceinline__ void gemm1_body(int gb, const float* __restrict__ x,
                                           const float* __restrict__ W1,
                                           __half* __restrict__ s1h,
                                           char* lds_raw) {
    f16* xh  = (f16*)lds_raw;              // [64][40] halves, 5120 B
    f16* xl  = (f16*)(lds_raw + 5120);     // [64][40] halves, 5120 B
    f16* wth = (f16*)(lds_raw + 10240);    // [64][40] halves: W^T hi chunk, 5120 B
    f16* wtl = (f16*)(lds_raw + 15360);    // [64][40] halves: W^T lo chunk, 5120 B

    const int t    = threadIdx.x;
    const int row0 = gb * 64;
    const int lane = t & 63;
    const int wv   = t >> 6;               // wave 0..3 owns rows wv*16..wv*16+15
    const int lr   = lane & 15;            // A row / B col within 16-tile
    const int kg   = lane >> 4;            // k-group: k = kg*8..kg*8+7

    f32x4 acc[4];
#pragma unroll
    for (int n = 0; n < 4; ++n) acc[n] = (f32x4){0.f, 0.f, 0.f, 0.f};

    for (int kt = 0; kt < 8; ++kt) {
        // ---- stage x chunk (64 rows x 32 k, fp32 -> hi/lo fp16): 512 float4 ----
#pragma unroll
        for (int i = 0; i < 2; ++i) {
            int L  = i * 256 + t;          // 0..511 = 64 rows x 8 float4
            int r  = L >> 3;
            int k4 = L & 7;
            int rg = row0 + r;
            float4 v = make_float4(0.f, 0.f, 0.f, 0.f);
            if (rg < N_NODES)
                v = ((const float4*)x)[(size_t)rg * 64 + kt * 8 + k4];
            union { f16 h[4]; unsigned long long u; } ph, pl;
            const float* vf = (const float*)&v;
#pragma unroll
            for (int c = 0; c < 4; ++c) {
                f16 hi = (f16)vf[c];
                ph.h[c] = hi;
                pl.h[c] = (f16)(vf[c] - (float)hi);
            }
            *(unsigned long long*)(&xh[r * 40 + k4 * 4]) = ph.u;
            *(unsigned long long*)(&xl[r * 40 + k4 * 4]) = pl.u;
        }
        // ---- stage W chunk transposed (32 k x 64 j -> W^T[j][k] hi/lo) ----
#pragma unroll
        for (int i = 0; i < 2; ++i) {
            int L  = i * 256 + t;          // 0..511 = 32 k x 16 float4
            int k  = L >> 4;
            int j4 = L & 15;
            float4 v = ((const float4*)W1)[(size_t)(kt * 32 + k) * 16 + j4];
            const float* vf = (const float*)&v;
#pragma unroll
            for (int c = 0; c < 4; ++c) {
                f16 hi = (f16)vf[c];
                wth[(j4 * 4 + c) * 40 + k] = hi;
                wtl[(j4 * 4 + c) * 40 + k] = (f16)(vf[c] - (float)hi);
            }
        }
        __syncthreads();

        f16x8 ah, al, bh[4], bl[4];
        ah = *(const f16x8*)(&xh[(wv * 16 + lr) * 40 + kg * 8]);
        al = *(const f16x8*)(&xl[(wv * 16 + lr) * 40 + kg * 8]);
#pragma unroll
        for (int n = 0; n < 4; ++n) {
            bh[n] = *(const f16x8*)(&wth[(n * 16 + lr) * 40 + kg * 8]);
            bl[n] = *(const f16x8*)(&wtl[(n * 16 + lr) * 40 + kg * 8]);
        }
#pragma unroll
        for (int n = 0; n < 4; ++n) {
            acc[n] = __builtin_amdgcn_mfma_f32_16x16x32_f16(ah, bh[n], acc[n], 0, 0, 0);
            acc[n] = __builtin_amdgcn_mfma_f32_16x16x32_f16(ah, bl[n], acc[n], 0, 0, 0);
            acc[n] = __builtin_amdgcn_mfma_f32_16x16x32_f16(al, bh[n], acc[n], 0, 0, 0);
        }
        __syncthreads();
    }

    // epilogue: LDS transpose, coalesced 16 B stores (no dis scale)
    // C/D layout: col = lane&15, row = (lane>>4)*4 + reg  [m89-verified]
    f16* ob = (f16*)lds_raw;               // [64][72] halves = 9216 B (aliases stage bufs)
#pragma unroll
    for (int r = 0; r < 4; ++r) {
        int rl = wv * 16 + kg * 4 + r;
#pragma unroll
        for (int n = 0; n < 4; ++n)
            ob[rl * 72 + n * 16 + lr] = (f16)(acc[n][r]);
    }
    __syncthreads();
#pragma unroll
    for (int i = 0; i < 2; ++i) {
        int L = i * 256 + t;               // 0..511 = 64 rows x 8 segs of 8 halves
        int r = L >> 3;
        int sg = L & 7;
        int rg = row0 + r;
        if (rg < N_NODES) {
            f16x8 v = *(const f16x8*)(&ob[r * 72 + sg * 8]);
            *(f16x8*)(s1h + (size_t)rg * HID + sg * 8) = v;
        }
    }
}

__global__ __launch_bounds__(256) void fused_pg(const int* __restrict__ row,
                                                const int* __restrict__ col,
                                                int* __restrict__ gcur,
                                                int* __restrict__ part,
                                                const float* __restrict__ x,
                                                const float* __restrict__ W1,
                                                __half* __restrict__ s1h) {
    __shared__ __align__(16) char smem[20480];
    const int bid = blockIdx.x;
    const int p = bid / 3;
    const int r = bid - p * 3;
    if (r == 0) {
        partition_body(p, row, col, gcur, part, smem);
    } else {
        int gb = 2 * p + (r - 1);
        if (gb < NG1) gemm1_body(gb, x, W1, s1h, smem);
    }
}

// ---------------- bucket_build: 782 blocks x 512 threads -------------------------
// After computing dis for its 128 nodes, each block also RESCALES the s1h rows
// it owns (s1h[n] *= dis[n]; 25.6 MB streamed, coalesced). This restores the
// invariant s1h[n] = dis[n]*(x@W1)[n] so gather1 keeps its measured-best
// pure-sum shape with no per-edge dis loads.
__global__ __launch_bounds__(512) void bucket_build(const int* __restrict__ gcur,
                                                    const int* __restrict__ part,
                                                    int* __restrict__ ptrb,
                                                    int* __restrict__ ptre,
                                                    float* __restrict__ dis,
                                                    int* __restrict__ srcs,
                                                    __half* __restrict__ s1h) {
    __shared__ int pcache[CAP];    // 18432 B: this bucket's packed edges
    __shared__ int lh[BNODES];     // per-node count
    __shared__ int lb[BNODES];     // exclusive scan (bucket-local base)
    __shared__ int lcur[BNODES];   // fill cursor
    __shared__ int ls[BNODES];
    __shared__ float ldis[BNODES]; // dis for this bucket's nodes
    const int b = blockIdx.x;
    const int t = threadIdx.x;
    if (t < BNODES) { lh[t] = 0; lcur[t] = 0; }
    __syncthreads();
    const int cnt = gcur[b];                 // relative count (gcur zeroed)
    const size_t pbase = (size_t)b * CAP;

    for (int i = t; i < cnt; i += 512) {
        int p = part[pbase + i];
        pcache[i] = p;
        atomicAdd(&lh[p >> 17], 1);
    }
    __syncthreads();

    int val = (t < BNODES) ? lh[t] : 0;
    if (t < BNODES) ls[t] = val;
    __syncthreads();
    for (int off = 1; off < BNODES; off <<= 1) {
        int add = (t >= off && t < BNODES) ? ls[t - off] : 0;
        __syncthreads();
        if (t < BNODES) ls[t] += add;
        __syncthreads();
    }
    if (t < BNODES) lb[t] = ls[t] - val;   // exclusive
    __syncthreads();

    int v = b * BNODES + t;
    if (t < BNODES) {
        float d = rsqrtf((float)val + 1.0f);   // +1 self-loop
        ldis[t] = d;
        if (v < N_NODES) {
            ptrb[v] = b * CAP + lb[t];
            ptre[v] = b * CAP + lb[t] + val;
            dis[v]  = d;
        }
    }
    __syncthreads();

    // scatter into srcs
    for (int i = t; i < cnt; i += 512) {
        int p    = pcache[i];
        int dlow = p >> 17;
        int src  = p & 0x1FFFF;
        int r    = atomicAdd(&lcur[dlow], 1);
        srcs[pbase + lb[dlow] + r] = src;
    }

    // rescale this bucket's s1h rows by dis (coalesced 16 B ops)
    {
        int nrows = N_NODES - b * BNODES;
        if (nrows > BNODES) nrows = BNODES;
        const int nwork = nrows * 8;           // 8 f16x8 segs per 64-half row
        for (int i = t; i < nwork; i += 512) {
            int r  = i >> 3;
            int sg = i & 7;
            __half* p = s1h + (size_t)(b * BNODES + r) * HID + sg * 8;
            f16x8 vv = *(const f16x8*)p;
            float d = ldis[r];
            f16x8 ov;
#pragma unroll
            for (int c = 0; c < 8; ++c) ov[c] = (f16)((float)vv[c] * d);
            *(f16x8*)p = ov;
        }
    }
}

// ---------------- gather1 + ELU + fused GEMM2 (measured-best shape) ---------------
// s1h rows pre-scaled by dis[src] (bucket_build). One coalesced srcs load per
// 64-edge block, __shfl broadcast, 8 gathers in flight.
__global__ __launch_bounds__(256) void gather1(const __half* __restrict__ s1h,
                                               const int* __restrict__ ptrb,
                                               const int* __restrict__ ptre,
                                               const int* __restrict__ srcs,
                                               const float* __restrict__ dis,
                                               const float* __restrict__ b1,
                                               const float* __restrict__ W2,
                                               __half* __restrict__ s2h) {
    __shared__ float w2lds[HID * OUTC];   // 8 KB: [k][jo]
    __shared__ float hbuf[4][HID];        // per-wave ELU'd h row

    const int t = threadIdx.x;
    {
        float4* l4 = (float4*)w2lds;
        const float4* s4 = (const float4*)W2;
        l4[t] = s4[t];
        l4[256 + t] = s4[256 + t];
    }
    __syncthreads();

    const int j = t & 63;
    const int w = t >> 6;
    const int l = j & 31;                 // half2 index within row (features 2l,2l+1)
    const int h = j >> 5;                 // edge-of-pair selector
    const int v = __builtin_amdgcn_readfirstlane(blockIdx.x * 4 + w);
    const __half2* s12 = (const __half2*)s1h;   // row stride 32 half2

    float2 acc;
    {
        float2 self = __half22float2(s12[(v << 5) | l]);
        acc = (h == 0) ? self : make_float2(0.f, 0.f);   // self-loop counted once
    }
    const int beg = ptrb[v];
    const int end = ptre[v];

    for (int base = beg; base < end; base += 64) {
        int mysrc = 0;
        if (base + j < end) mysrc = srcs[base + j];   // one coalesced load / 64 edges
        int nk = end - base;
        if (nk > 64) nk = 64;
        const int full = nk >> 1;                     // complete pairs
        int i = 0;
        // unmasked 8-pair (16-edge) blocks: 8 gathers in flight, no tail logic
        for (; i + 8 <= full; i += 8) {
            int s  = 2 * i + h;
            int a0 = __shfl(mysrc, s,      64);
            int a1 = __shfl(mysrc, s + 2,  64);
            int a2 = __shfl(mysrc, s + 4,  64);
            int a3 = __shfl(mysrc, s + 6,  64);
            int a4 = __shfl(mysrc, s + 8,  64);
            int a5 = __shfl(mysrc, s + 10, 64);
            int a6 = __shfl(mysrc, s + 12, 64);
            int a7 = __shfl(mysrc, s + 14, 64);
            float2 g0 = __half22float2(s12[(a0 << 5) | l]);
            float2 g1 = __half22float2(s12[(a1 << 5) | l]);
            float2 g2 = __half22float2(s12[(a2 << 5) | l]);
            float2 g3 = __half22float2(s12[(a3 << 5) | l]);
            float2 g4 = __half22float2(s12[(a4 << 5) | l]);
            float2 g5 = __half22float2(s12[(a5 << 5) | l]);
            float2 g6 = __half22float2(s12[(a6 << 5) | l]);
            float2 g7 = __half22float2(s12[(a7 << 5) | l]);
            acc.x += ((g0.x + g1.x) + (g2.x + g3.x)) + ((g4.x + g5.x) + (g6.x + g7.x));
            acc.y += ((g0.y + g1.y) + (g2.y + g3.y)) + ((g4.y + g5.y) + (g6.y + g7.y));
        }
        // one masked 8-pair block covers the remaining <=15 slots (incl. odd edge)
        if (2 * i < nk) {
            const int last = nk - 1;
#pragma unroll
            for (int u = 0; u < 8; ++u) {
                int s  = 2 * (i + u) + h;
                int sc = s < last ? s : last;
                int a  = __shfl(mysrc, sc, 64);
                float wgt = (s < nk) ? 1.f : 0.f;
                float2 g = __half22float2(s12[(a << 5) | l]);
                acc.x = fmaf(wgt, g.x, acc.x);
                acc.y = fmaf(wgt, g.y, acc.y);
            }
        }
    }
    acc.x += __shfl_xor(acc.x, 32, 64);   // even-edge + odd-edge partials
    acc.y += __shfl_xor(acc.y, 32, 64);

    float dv = dis[v];
    float2 bb = *(const float2*)(b1 + 2 * l);
    float t0 = dv * acc.x + bb.x;
    float t1 = dv * acc.y + bb.y;
    float h0 = t0 > 0.f ? t0 : (expf(t0) - 1.f);
    float h1 = t1 > 0.f ? t1 : (expf(t1) - 1.f);
    if (h == 0) {
        hbuf[w][2 * l]     = h0;
        hbuf[w][2 * l + 1] = h1;
    }

    // ---- fused gemm2: s2[v][jo] = dis[v] * sum_k hh[k] * W2[k][jo]
    const int jo = j & 31;
    const int kb = (j >> 5) * 32;          // lower lanes: k 0..31, upper: 32..63
    float p = 0.f;
#pragma unroll
    for (int kk = 0; kk < 32; ++kk)
        p += hbuf[w][kb + kk] * w2lds[(kb + kk) * OUTC + jo];
    p += __shfl_xor(p, 32, 64);            // combine the two k-halves
    if (j < 32) {
        s2h[(size_t)v * OUTC + jo] = __float2half(dv * p);
    }
}

// ---------------- gather2 + ELU + final projection --------------------------------
__global__ __launch_bounds__(256) void gather2(const __half* __restrict__ s2h,
                                               const int* __restrict__ ptrb,
                                               const int* __restrict__ ptre,
                                               const int* __restrict__ srcs,
                                               const float* __restrict__ dis,
                                               const float* __restrict__ b2,
                                               const float* __restrict__ Wc,
                                               const float* __restrict__ bc,
                                               float* __restrict__ out) {
    const int j = threadIdx.x & 63;
    const int w = threadIdx.x >> 6;
    const int l = j & 3;                  // feature octet within row
    const int e = j >> 2;                 // edge-of-16 (0..15)
    const int v = __builtin_amdgcn_readfirstlane(blockIdx.x * 4 + w);
    const float4* s24 = (const float4*)s2h;   // row stride 4 float4s (64 B)

    float acc[8] = {0.f, 0.f, 0.f, 0.f, 0.f, 0.f, 0.f, 0.f};
    if (e == 0) acc8(acc, s24[(v << 2) | l]);   // self-loop

    const int beg = ptrb[v];
    const int end = ptre[v];
    for (int base = beg; base < end; base += 64) {
        int mys = 0;
        if (base + j < end) mys = srcs[base + j];
        int nk = end - base;
        if (nk > 64) nk = 64;
        int off = 0;
        for (; off + 32 <= nk; off += 32) {          // unmasked 32-edge blocks
            int a0 = __shfl(mys, off + e,      64);
            int a1 = __shfl(mys, off + 16 + e, 64);
            float4 r0 = s24[(a0 << 2) | l];
            float4 r1 = s24[(a1 << 2) | l];
            acc8(acc, r0);
            acc8(acc, r1);
        }
        if (off < nk) {                               // masked tail (<=31 edges)
            const int last = nk - 1;
            int s0 = off + e, s1 = off + 16 + e;
            int a0 = __shfl(mys, s0 < last ? s0 : last, 64);
            int a1 = __shfl(mys, s1 < last ? s1 : last, 64);
            if (s0 < nk) acc8(acc, s24[(a0 << 2) | l]);
            if (s1 < nk) acc8(acc, s24[(a1 << 2) | l]);
        }
    }
#pragma unroll
    for (int i = 0; i < 8; ++i) {
        acc[i] += __shfl_xor(acc[i], 4, 64);
        acc[i] += __shfl_xor(acc[i], 8, 64);
        acc[i] += __shfl_xor(acc[i], 16, 64);
        acc[i] += __shfl_xor(acc[i], 32, 64);
    }

    float dv = dis[v];
    float4 ba = ((const float4*)b2)[2 * l];
    float4 bb = ((const float4*)b2)[2 * l + 1];
    float4 wa = ((const float4*)Wc)[2 * l];
    float4 wb = ((const float4*)Wc)[2 * l + 1];
    const float* bf = (const float*)&ba;
    const float* bg = (const float*)&bb;
    const float* wf = (const float*)&wa;
    const float* wg = (const float*)&wb;
    float p = 0.f;
#pragma unroll
    for (int i = 0; i < 8; ++i) {
        float bias = (i < 4) ? bf[i] : bg[i - 4];
        float wc   = (i < 4) ? wf[i] : wg[i - 4];
        float tt = dv * acc[i] + bias;
        float hh = tt > 0.f ? tt : (expf(tt) - 1.f);
        p += hh * wc;
    }
    p += __shfl_xor(p, 1, 64);   // reduce over the 4 feature-lanes
    p += __shfl_xor(p, 2, 64);
    if (j == 0) out[v] = p + bc[0];
}

extern "C" void kernel_launch(void* const* d_in, const int* in_sizes, int n_in,
                              void* d_out, int out_size, void* d_ws, size_t ws_size,
                              hipStream_t stream) {
    const float* x  = (const float*)d_in[0];
    const int*   ei = (const int*)d_in[1];
    const float* W1 = (const float*)d_in[2];
    const float* b1 = (const float*)d_in[3];
    const float* W2 = (const float*)d_in[4];
    const float* b2 = (const float*)d_in[5];
    const float* Wc = (const float*)d_in[6];
    const float* bc = (const float*)d_in[7];
    float* out = (float*)d_out;

    const int* row = ei;            // edge_index[0] = source
    const int* col = ei + N_EDGES;  // edge_index[1] = target

    char* ws = (char*)d_ws;
    int*    ptrb = (int*)   (ws + OFF_PTRB);
    int*    ptre = (int*)   (ws + OFF_PTRE);
    int*    gcur = (int*)   (ws + OFF_GCUR);
    float*  dis  = (float*) (ws + OFF_DIS);
    int*    srcs = (int*)   (ws + OFF_SRC);
    int*    part = (int*)   (ws + OFF_PART);
    __half* s1h  = (__half*)(ws + OFF_S1);
    __half* s2h  = (__half*)(ws + OFF_S2);

    hipMemsetAsync(gcur, 0, (size_t)NBUCK * 4, stream);
    fused_pg    <<<NPART * 3, 256, 0, stream>>>(row, col, gcur, part, x, W1, s1h);
    bucket_build<<<NBUCK, 512, 0, stream>>>(gcur, part, ptrb, ptre, dis, srcs, s1h);

    gather1<<<N_NODES / 4, 256, 0, stream>>>(s1h, ptrb, ptre, srcs, dis, b1, W2, s2h);
    gather2<<<N_NODES / 4, 256, 0, stream>>>(s2h, ptrb, ptre, srcs, dis, b2, Wc, bc, out);
}